// Round 11
// baseline (362.510 us; speedup 1.0000x reference)
//
#include <hip/hip_runtime.h>
#include <stdint.h>

#define N_NODES 100000
#define N_EDGES 600000
#define FEAT 128
#define GRID_F 1024
#define NWTASK 37500     // 600000 edges / 16 per wave-task

typedef __attribute__((ext_vector_type(8))) short short8;
typedef __attribute__((ext_vector_type(4))) float floatx4;

__device__ __forceinline__ short f2bf(float f) {
    unsigned u = __builtin_bit_cast(unsigned, f);
    u = (u + 0x7FFFu + ((u >> 16) & 1u)) >> 16;   // RNE to bf16
    return (short)u;
}

// ONE kernel: per-edge h = x[r].W1t + x[c].W1b + b1 via MFMA (X rows gathered
// directly; Y never materialized), then out = sigmoid(relu(h).W2 + b2).
// W1 (fp32) converted once per block into chunk-major bf16 LDS (R9-verified code).
// Each wave owns 16 edges/iter: A1 = x[rows r] (16x128), A2 = x[rows c],
// acc = A1*W1t + A2*W1b accumulated in fp32; head reduces in-register.
// MFMA mapping (R1/R5/R6-verified): D[m = q*4+r4][n = nt*16+nl].
__global__ __launch_bounds__(512, 2) void fused_edge_kernel(
    const float* __restrict__ x, const int* __restrict__ eidx,
    const float* __restrict__ w1, const float* __restrict__ b1,
    const float* __restrict__ w2, const float* __restrict__ b2,
    float* __restrict__ out)
{
    __shared__ short lds_b[16 * 256 * 8];   // chunk-major [c=k/8][n=256], 64 KB

    const int tid  = threadIdx.x;
    const int lane = tid & 63;
    const int wave = tid >> 6;           // 0..7
    const int nl   = lane & 15;
    const int q    = lane >> 4;

    // ---- stage W1 -> bf16 LDS, chunk-major (R9 verbatim) ----
    // lds_b[(c*256+n)*8 + j] = Wbt[n][c*8+j] ; Wbt[n][k] = (n<128)?W1[k][n]:W1[128+k][n-128]
#pragma unroll
    for (int it = 0; it < 8; ++it) {
        int t = it * 512 + tid;
        int n = t & 255, c = t >> 8;
        const float* src = (n < 128) ? (w1 + (c * 8) * 128 + n)
                                     : (w1 + (128 + c * 8) * 128 + (n - 128));
        short8 v;
#pragma unroll
        for (int j = 0; j < 8; ++j) v[j] = f2bf(src[j * 128]);
        *(short8*)(lds_b + t * 8) = v;
    }

    // per-lane head constants: feat col f = nt*16 + nl
    float w2v[8], b1v[8];
#pragma unroll
    for (int nt = 0; nt < 8; ++nt) {
        w2v[nt] = w2[nt * 16 + nl];
        b1v[nt] = b1[nt * 16 + nl];
    }
    const float bias2 = b2[0];

    __syncthreads();   // W ready; main loop is barrier-free

    const int w0     = blockIdx.x * 8 + wave;
    const int wstep  = GRID_F * 8;       // 8192 waves

    for (int t = w0; t < NWTASK; t += wstep) {
        const int e0 = t * 16;           // NWTASK*16 == N_EDGES exactly, no tail
        const int r = eidx[e0 + nl];
        const int c = eidx[N_EDGES + e0 + nl];
        const float* pr = x + (size_t)r * FEAT;
        const float* pc = x + (size_t)c * FEAT;

        // gather A-rows: lane (nl,q) reads k = s*32+8q+j of rows r[nl], c[nl]
        floatx4 xr[8], xc[8];
#pragma unroll
        for (int s = 0; s < 4; ++s) {
            xr[2 * s]     = *(const floatx4*)(pr + s * 32 + q * 8);
            xr[2 * s + 1] = *(const floatx4*)(pr + s * 32 + q * 8 + 4);
            xc[2 * s]     = *(const floatx4*)(pc + s * 32 + q * 8);
            xc[2 * s + 1] = *(const floatx4*)(pc + s * 32 + q * 8 + 4);
        }
        short8 a1[4], a2[4];
#pragma unroll
        for (int s = 0; s < 4; ++s) {
            short8 v1, v2;
#pragma unroll
            for (int j = 0; j < 8; ++j) {
                v1[j] = f2bf(xr[2 * s + (j >> 2)][j & 3]);
                v2[j] = f2bf(xc[2 * s + (j >> 2)][j & 3]);
            }
            a1[s] = v1; a2[s] = v2;
        }

        floatx4 acc[8];
#pragma unroll
        for (int nt = 0; nt < 8; ++nt) acc[nt] = (floatx4)(0.0f);

        // h[e][f] = sum_k x[r][k] W1t[k][f]  (B = Wbt cols 0..127)
#pragma unroll
        for (int s = 0; s < 4; ++s) {
            const int crow = (s * 4 + q) << 8;
#pragma unroll
            for (int nt = 0; nt < 8; ++nt) {
                short8 bf = *(const short8*)(lds_b + ((crow + nt * 16 + nl) << 3));
                acc[nt] = __builtin_amdgcn_mfma_f32_16x16x32_bf16(a1[s], bf, acc[nt], 0, 0, 0);
            }
        }
        //        += sum_k x[c][k] W1b[k][f]  (B = Wbt cols 128..255)
#pragma unroll
        for (int s = 0; s < 4; ++s) {
            const int crow = (s * 4 + q) << 8;
#pragma unroll
            for (int nt = 0; nt < 8; ++nt) {
                short8 bf = *(const short8*)(lds_b + ((crow + 128 + nt * 16 + nl) << 3));
                acc[nt] = __builtin_amdgcn_mfma_f32_16x16x32_bf16(a2[s], bf, acc[nt], 0, 0, 0);
            }
        }

        // head: lane holds edges m=q*4+r4 (r4=0..3), feat col f=nt*16+nl
        float p[4] = {0.0f, 0.0f, 0.0f, 0.0f};
#pragma unroll
        for (int nt = 0; nt < 8; ++nt) {
#pragma unroll
            for (int r4 = 0; r4 < 4; ++r4) {
                float h = acc[nt][r4] + b1v[nt];
                p[r4] = fmaf(fmaxf(h, 0.0f), w2v[nt], p[r4]);
            }
        }
#pragma unroll
        for (int d = 1; d < 16; d <<= 1) {
#pragma unroll
            for (int r4 = 0; r4 < 4; ++r4) p[r4] += __shfl_xor(p[r4], d);
        }

        if (nl == 0) {   // lanes q=0..3 store edges e0+q*4 .. +3
            floatx4 o;
            o[0] = 1.0f / (1.0f + __expf(-(p[0] + bias2)));
            o[1] = 1.0f / (1.0f + __expf(-(p[1] + bias2)));
            o[2] = 1.0f / (1.0f + __expf(-(p[2] + bias2)));
            o[3] = 1.0f / (1.0f + __expf(-(p[3] + bias2)));
            *(floatx4*)(out + e0 + q * 4) = o;
        }
    }
}

extern "C" void kernel_launch(void* const* d_in, const int* in_sizes, int n_in,
                              void* d_out, int out_size, void* d_ws, size_t ws_size,
                              hipStream_t stream) {
    const float* x  = (const float*)d_in[0];
    const int*   ei = (const int*)d_in[1];
    const float* W1 = (const float*)d_in[2];
    const float* b1 = (const float*)d_in[3];
    const float* W2 = (const float*)d_in[4];
    const float* b2 = (const float*)d_in[5];
    float* out = (float*)d_out;

    fused_edge_kernel<<<GRID_F, 512, 0, stream>>>(x, ei, W1, b1, W2, b2, out);
}

// Round 12
// 137.388 us; speedup vs baseline: 2.6386x; 2.6386x over previous
//
#include <hip/hip_runtime.h>
#include <stdint.h>

#define N_NODES 100000
#define N_EDGES 600000
#define FEAT 128
#define BLK_M 128

typedef __attribute__((ext_vector_type(8))) short short8;
typedef __attribute__((ext_vector_type(4))) float floatx4;
typedef __attribute__((ext_vector_type(2))) float floatx2;

__device__ __forceinline__ short f2bf(float f) {
    unsigned u = __builtin_bit_cast(unsigned, f);
    u = (u + 0x7FFFu + ((u >> 16) & 1u)) >> 16;   // RNE to bf16
    return (short)u;
}

// Y[100000][256] fp8-e4m3 = quant( X @ [W1t | W1b] + [b1|0] ).  R9-verified GEMM
// structure (W fp32->bf16 chunk-major LDS in prologue, operand-swapped MFMA);
// epilogue quantizes to OCP e4m3 via HW v_cvt_pk_fp8_f32 (RNE) -> row = 256 B,
// halving the edge phase's gathered bytes (the measured ~3.2 TB/s fabric ceiling).
__global__ __launch_bounds__(512, 4) void node_gemm_kernel(
    const float* __restrict__ x, const float* __restrict__ w1,
    const float* __restrict__ b1, unsigned char* __restrict__ y)
{
    __shared__ short lds_b[16 * 256 * 8];   // chunk-major [c=k/8][n], 64 KB

    const int tid  = threadIdx.x;
    const int lane = tid & 63;
    const int wave = tid >> 6;           // 0..7
    const int nl   = lane & 15;
    const int q    = lane >> 4;
    const int m0   = blockIdx.x * BLK_M + wave * 16;

    // X loads issued first: HBM latency overlaps the W conversion below
    const int node = m0 + nl;
    const int nsrc = (node < N_NODES) ? node : 0;
    floatx4 xv[8];
#pragma unroll
    for (int s = 0; s < 4; ++s) {
        const float* p = x + (size_t)nsrc * FEAT + s * 32 + q * 8;
        xv[2 * s]     = *(const floatx4*)(p);
        xv[2 * s + 1] = *(const floatx4*)(p + 4);
    }

    // Convert W1 -> lds_b: element (c*256+n)*8 + j == Wbt[n][c*8+j]
#pragma unroll
    for (int it = 0; it < 8; ++it) {
        int t = it * 512 + tid;          // 4096 (c,n) groups
        int n = t & 255, c = t >> 8;
        const float* src = (n < 128) ? (w1 + (c * 8) * 128 + n)
                                     : (w1 + (128 + c * 8) * 128 + (n - 128));
        short8 v;
#pragma unroll
        for (int j = 0; j < 8; ++j) v[j] = f2bf(src[j * 128]);
        *(short8*)(lds_b + t * 8) = v;   // lane-consecutive 16B, conflict-free
    }

    __syncthreads();

    // convert X to bf16 B-fragments: a[s][j] = X[node][32s + 8q + j]
    short8 a[4];
#pragma unroll
    for (int s = 0; s < 4; ++s) {
        short8 av;
#pragma unroll
        for (int j = 0; j < 8; ++j) av[j] = f2bf(xv[2 * s + (j >> 2)][j & 3]);
        a[s] = av;
    }

    floatx4 acc[16];
#pragma unroll
    for (int nt = 0; nt < 16; ++nt) acc[nt] = (floatx4)(0.0f);

#pragma unroll
    for (int s = 0; s < 4; ++s) {
        const int crow = (s * 4 + q) << 8;   // chunk c = s*4+q, row base c*256
#pragma unroll
        for (int nt = 0; nt < 16; ++nt) {
            short8 wf = *(const short8*)(lds_b + ((crow + nt * 16 + nl) << 3));
            // D[row = n_local = q*4+r][col = m_local = nl]
            acc[nt] = __builtin_amdgcn_mfma_f32_16x16x32_bf16(wf, a[s], acc[nt], 0, 0, 0);
        }
    }

    // Epilogue: lane owns node = m0+nl, cols n = nt*16 + q*4 + r4 -> one 4B fp8
    // dword per nt (HW pack: slot0 -> low byte on both encode and decode sides)
    if (node < N_NODES) {
        unsigned char* yr = y + (size_t)node * 256 + q * 4;
#pragma unroll
        for (int nt = 0; nt < 8; ++nt) {     // u-half: fold b1
            floatx4 bb = *(const floatx4*)(b1 + nt * 16 + q * 4);
            int d = __builtin_amdgcn_cvt_pk_fp8_f32(acc[nt][0] + bb[0],
                                                    acc[nt][1] + bb[1], 0, false);
            d = __builtin_amdgcn_cvt_pk_fp8_f32(acc[nt][2] + bb[2],
                                                acc[nt][3] + bb[3], d, true);
            *(int*)(yr + nt * 16) = d;
        }
#pragma unroll
        for (int nt = 8; nt < 16; ++nt) {    // v-half
            int d = __builtin_amdgcn_cvt_pk_fp8_f32(acc[nt][0], acc[nt][1], 0, false);
            d = __builtin_amdgcn_cvt_pk_fp8_f32(acc[nt][2], acc[nt][3], d, true);
            *(int*)(yr + nt * 16) = d;
        }
    }
}

// decode 8 fp8 bytes (one uint2) -> 8 floats via HW v_cvt_pk_f32_fp8
__device__ __forceinline__ void dec8(uint2 w, float* f) {
    floatx2 p0 = __builtin_amdgcn_cvt_pk_f32_fp8(w.x, false);
    floatx2 p1 = __builtin_amdgcn_cvt_pk_f32_fp8(w.x, true);
    floatx2 p2 = __builtin_amdgcn_cvt_pk_f32_fp8(w.y, false);
    floatx2 p3 = __builtin_amdgcn_cvt_pk_f32_fp8(w.y, true);
    f[0] = p0.x; f[1] = p0.y; f[2] = p1.x; f[3] = p1.y;
    f[4] = p2.x; f[5] = p2.y; f[6] = p3.x; f[7] = p3.y;
}

// Per-edge: out = sigmoid(relu(Yu[r] + Yv[c]) . W2 + b2)   (b1 pre-folded into Yu)
// R6-verified batch-4 structure; gathers are now 8 B fp8 (half the bytes).
__global__ __launch_bounds__(256) void edge_kernel(
    const unsigned char* __restrict__ y, const int* __restrict__ eidx,
    const float* __restrict__ w2, const float* __restrict__ b2,
    float* __restrict__ out)
{
    const int l = threadIdx.x & 15;

    float w2r[8];
#pragma unroll
    for (int j = 0; j < 8; ++j) w2r[j] = w2[l * 8 + j];
    const float bias2 = b2[0];

    const int slot   = blockIdx.x * 16 + (threadIdx.x >> 4);
    const int nslots = gridDim.x * 16;               // 32768

    for (int eb = slot * 4; eb < N_EDGES; eb += nslots * 4) {
        int4 rr = *(const int4*)(eidx + eb);
        int4 cc = *(const int4*)(eidx + N_EDGES + eb);

        uint2 u0 = *(const uint2*)(y + (size_t)rr.x * 256 + l * 8);
        uint2 u1 = *(const uint2*)(y + (size_t)rr.y * 256 + l * 8);
        uint2 u2 = *(const uint2*)(y + (size_t)rr.z * 256 + l * 8);
        uint2 u3 = *(const uint2*)(y + (size_t)rr.w * 256 + l * 8);
        uint2 v0 = *(const uint2*)(y + (size_t)cc.x * 256 + 128 + l * 8);
        uint2 v1 = *(const uint2*)(y + (size_t)cc.y * 256 + 128 + l * 8);
        uint2 v2 = *(const uint2*)(y + (size_t)cc.z * 256 + 128 + l * 8);
        uint2 v3 = *(const uint2*)(y + (size_t)cc.w * 256 + 128 + l * 8);

        float fu[8], fv[8];
        float p0 = 0.0f, p1 = 0.0f, p2 = 0.0f, p3 = 0.0f;

        dec8(u0, fu); dec8(v0, fv);
#pragma unroll
        for (int j = 0; j < 8; ++j)
            p0 = fmaf(fmaxf(fu[j] + fv[j], 0.0f), w2r[j], p0);
        dec8(u1, fu); dec8(v1, fv);
#pragma unroll
        for (int j = 0; j < 8; ++j)
            p1 = fmaf(fmaxf(fu[j] + fv[j], 0.0f), w2r[j], p1);
        dec8(u2, fu); dec8(v2, fv);
#pragma unroll
        for (int j = 0; j < 8; ++j)
            p2 = fmaf(fmaxf(fu[j] + fv[j], 0.0f), w2r[j], p2);
        dec8(u3, fu); dec8(v3, fv);
#pragma unroll
        for (int j = 0; j < 8; ++j)
            p3 = fmaf(fmaxf(fu[j] + fv[j], 0.0f), w2r[j], p3);

#pragma unroll
        for (int d = 1; d < 16; d <<= 1) {
            p0 += __shfl_xor(p0, d);
            p1 += __shfl_xor(p1, d);
            p2 += __shfl_xor(p2, d);
            p3 += __shfl_xor(p3, d);
        }

        if (l == 0) {
            floatx4 o;
            o[0] = 1.0f / (1.0f + __expf(-(p0 + bias2)));
            o[1] = 1.0f / (1.0f + __expf(-(p1 + bias2)));
            o[2] = 1.0f / (1.0f + __expf(-(p2 + bias2)));
            o[3] = 1.0f / (1.0f + __expf(-(p3 + bias2)));
            *(floatx4*)(out + eb) = o;
        }
    }
}

extern "C" void kernel_launch(void* const* d_in, const int* in_sizes, int n_in,
                              void* d_out, int out_size, void* d_ws, size_t ws_size,
                              hipStream_t stream) {
    const float* x  = (const float*)d_in[0];
    const int*   ei = (const int*)d_in[1];
    const float* W1 = (const float*)d_in[2];
    const float* b1 = (const float*)d_in[3];
    const float* W2 = (const float*)d_in[4];
    const float* b2 = (const float*)d_in[5];
    float* out = (float*)d_out;

    unsigned char* yq = (unsigned char*)d_ws;           // 100000*256 B = 25.6 MB

    int mblocks = (N_NODES + BLK_M - 1) / BLK_M;        // 782
    node_gemm_kernel<<<mblocks, 512, 0, stream>>>(x, W1, b1, yq);

    edge_kernel<<<2048, 256, 0, stream>>>(yq, ei, W2, b2, out);
}